// Round 5
// baseline (114.350 us; speedup 1.0000x reference)
//
#include <hip/hip_runtime.h>

// Deformable conv, B=16 C=64 H=W=64, COUT=128, K=3 s=1 p=1 d=1.
// R5: software pipeline in deform_main (T14 async-stage split):
//   colf double-buffered; kk+1's 8x16B gathers ISSUED before kk's MFMA
//   cluster, converted+written to LDS after -> L2 latency hides under MFMA;
//   ONE barrier per kk (was 2). xt stays bf16 NHWC + XCD swizzle (R4).
//   GEMM: mfma_f32_16x16x32_bf16, B-frags global->reg, fp32 accum,
//   LDS-transpose epilogue, coalesced dwordx4 stores.

typedef short bf8 __attribute__((ext_vector_type(8)));   // 8 bf16 (4 VGPR)
typedef float f32x4 __attribute__((ext_vector_type(4)));
typedef unsigned short u16;
typedef u16 u16x8 __attribute__((ext_vector_type(8)));

__device__ inline u16 f2bf(float f) {                    // RNE f32 -> bf16
    unsigned u = __float_as_uint(f);
    return (u16)((u + 0x7FFFu + ((u >> 16) & 1u)) >> 16);
}
__device__ inline float bf2f(u16 v) {
    return __uint_as_float(((unsigned)v) << 16);
}

__global__ __launch_bounds__(256) void transpose_x_kernel(const float* __restrict__ x,
                                                          u16* __restrict__ xtb) {
    __shared__ float tile[64][65];
    int bid = blockIdx.x;            // b*64 + y
    int t = threadIdx.x;
    int b = bid >> 6, y = bid & 63;
    const float* xb = x + (size_t)b * 262144 + (size_t)y * 64;  // x[b][0][y][0]
#pragma unroll
    for (int it = 0; it < 16; ++it) {            // 16*256 = 4096 = 64c*64w
        int idx = t + it * 256;
        int c = idx >> 6, w = idx & 63;
        tile[c][w] = xb[(size_t)c * 4096 + w];
    }
    __syncthreads();
    unsigned* dst = (unsigned*)(xtb + (size_t)bid * 4096);   // xtb[b][y][w][c]
#pragma unroll
    for (int it = 0; it < 8; ++it) {             // 2 c's per thread -> 4B stores
        int p = t + it * 256;                    // pair index: w = p>>5, c0 = (p&31)*2
        int w = p >> 5, c0 = (p & 31) * 2;
        unsigned lo = f2bf(tile[c0][w]);
        unsigned hi = f2bf(tile[c0 + 1][w]);
        dst[p] = lo | (hi << 16);
    }
}

// wf[kk][octile(8)][kstep(2)][lane(64)][i(8)] = bf16(weight[oc][c][kk])
//   oc = octile*16 + (lane&15); c = kstep*32 + (lane>>4)*8 + i
__global__ __launch_bounds__(256) void build_wfrag(const float* __restrict__ wgt,
                                                   short* __restrict__ wf) {
    int idx = blockIdx.x * 256 + threadIdx.x;    // 73728 total
    int i = idx & 7;
    int lane = (idx >> 3) & 63;
    int ks = (idx >> 9) & 1;
    int oct = (idx >> 10) & 7;
    int kk = idx >> 13;
    int oc = oct * 16 + (lane & 15);
    int c = ks * 32 + (lane >> 4) * 8 + i;
    wf[idx] = (short)f2bf(wgt[((size_t)oc * 64 + c) * 9 + kk]);
}

__global__ __launch_bounds__(256) void deform_main(const u16* __restrict__ xtb,
                                                   const float* __restrict__ offset,
                                                   const short* __restrict__ wf,
                                                   float* __restrict__ out) {
    // colf: 2 bufs * (4 pxtile * 2 kstep * 64 lane * 16B) = 16384 B
    // off_s: 18*64 f32 = 4608 B at +16384
    // epilogue reuses smem: per-wave f32[16][68] = 4352 B at wave*4352
    __shared__ __align__(16) char smem[20992];
    short* colf = (short*)smem;
    float* off_s = (float*)(smem + 16384);

    // XCD-aware swizzle: nwg=1024, 8 XCDs -> XCD k owns batch images {2k,2k+1}
    int wg = blockIdx.x;
    int wgid = (wg & 7) * 128 + (wg >> 3);
    int b = wgid >> 6, ho = wgid & 63;
    int t = threadIdx.x;
    int wave = t >> 6, lane = t & 63;

    {   // stage offsets: offset[b][ch][ho][wo], ch = 2*kk + {0:y,1:x}
        const float* ob = offset + (size_t)b * 18 * 4096 + ho * 64;
        for (int idx = t; idx < 18 * 64; idx += 256)
            off_s[idx] = ob[(idx >> 6) * 4096 + (idx & 63)];
    }
    __syncthreads();

    f32x4 acc[4][2];
#pragma unroll
    for (int m = 0; m < 4; ++m)
#pragma unroll
        for (int j = 0; j < 2; ++j) acc[m][j] = (f32x4)0.f;

    // producer mapping: px = t>>2 (wo), cq = t&3 (16-channel quad)
    const int px = t >> 2, cq = t & 3;
    const int pxt = px >> 4, wo15 = px & 15, ks_p = cq >> 1, kgb = (cq & 1) * 2;
    const u16* xb = xtb + (size_t)b * 262144;    // xtb[b][y][x][c] bf16
    // LDS dest (shorts offset) for this thread's two A-frag chunks
    const int cbase0 = ((pxt * 2 + ks_p) * 64 + ((kgb + 0) << 4 | wo15)) * 8;
    const int cbase1 = ((pxt * 2 + ks_p) * 64 + ((kgb + 1) << 4 | wo15)) * 8;

    // gather state for the in-flight kk tile
    u16x8 g00a, g01a, g10a, g11a, g00b, g01b, g10b, g11b;
    float w00, w01, w10, w11;

#define GATHER_ISSUE(KK)                                                        \
    {                                                                           \
        int ky = (KK) / 3, kx = (KK) - ky * 3;                                  \
        float py = off_s[(2 * (KK)) * 64 + px] + (float)(ho - 1 + ky);          \
        float sx = off_s[(2 * (KK) + 1) * 64 + px] + (float)(px - 1 + kx);      \
        float y0f = floorf(py), x0f = floorf(sx);                               \
        float ly = py - y0f, lx = sx - x0f;                                     \
        int y0 = (int)y0f, x0 = (int)x0f;                                       \
        int y1 = y0 + 1, x1 = x0 + 1;                                           \
        w00 = (1.f - ly) * (1.f - lx); w01 = (1.f - ly) * lx;                   \
        w10 = ly * (1.f - lx); w11 = ly * lx;                                   \
        bool vy0 = (y0 >= 0) & (y0 < 64), vy1 = (y1 >= 0) & (y1 < 64);          \
        bool vx0 = (x0 >= 0) & (x0 < 64), vx1 = (x1 >= 0) & (x1 < 64);          \
        if (!(vy0 & vx0)) w00 = 0.f;                                            \
        if (!(vy0 & vx1)) w01 = 0.f;                                            \
        if (!(vy1 & vx0)) w10 = 0.f;                                            \
        if (!(vy1 & vx1)) w11 = 0.f;                                            \
        int y0c = min(max(y0, 0), 63), y1c = min(max(y1, 0), 63);               \
        int x0c = min(max(x0, 0), 63), x1c = min(max(x1, 0), 63);               \
        const u16x8* q00 = (const u16x8*)(xb + ((y0c * 64 + x0c) * 64) + cq * 16); \
        const u16x8* q01 = (const u16x8*)(xb + ((y0c * 64 + x1c) * 64) + cq * 16); \
        const u16x8* q10 = (const u16x8*)(xb + ((y1c * 64 + x0c) * 64) + cq * 16); \
        const u16x8* q11 = (const u16x8*)(xb + ((y1c * 64 + x1c) * 64) + cq * 16); \
        g00a = q00[0]; g01a = q01[0]; g10a = q10[0]; g11a = q11[0];             \
        g00b = q00[1]; g01b = q01[1]; g10b = q10[1]; g11b = q11[1];             \
    }

#define INTERP_WRITE(BUF)                                                       \
    {                                                                           \
        short* cb = colf + (BUF) * 4096;                                        \
        bf8 va, vb;                                                             \
        _Pragma("unroll")                                                       \
        for (int i = 0; i < 8; ++i) {                                           \
            float ra = w00 * bf2f(g00a[i]) + w01 * bf2f(g01a[i]) +              \
                       w10 * bf2f(g10a[i]) + w11 * bf2f(g11a[i]);               \
            va[i] = (short)f2bf(ra);                                            \
            float rb = w00 * bf2f(g00b[i]) + w01 * bf2f(g01b[i]) +              \
                       w10 * bf2f(g10b[i]) + w11 * bf2f(g11b[i]);               \
            vb[i] = (short)f2bf(rb);                                            \
        }                                                                       \
        *(bf8*)(cb + cbase0) = va;                                              \
        *(bf8*)(cb + cbase1) = vb;                                              \
    }

    // ---- prologue: fill buf 0 with kk=0 ----
    GATHER_ISSUE(0);
    INTERP_WRITE(0);
    __syncthreads();

    for (int kk = 0; kk < 9; ++kk) {
        int cur = kk & 1, nxt = cur ^ 1;
        // issue next tile's gathers EARLY (drain under B-frag loads + MFMA)
        if (kk < 8) GATHER_ISSUE(kk + 1);

        // B-fragments: global -> reg (L2-resident, lane-linear)
        bf8 bfr0[2], bfr1[2];
#pragma unroll
        for (int ksi = 0; ksi < 2; ++ksi) {
            bfr0[ksi] = *(const bf8*)(wf + ((((kk * 8 + 2 * wave) * 2) + ksi) * 64 + lane) * 8);
            bfr1[ksi] = *(const bf8*)(wf + ((((kk * 8 + 2 * wave + 1) * 2) + ksi) * 64 + lane) * 8);
        }

        // MFMA: wave owns 64px x 32oc (octiles 2w, 2w+1) on buf cur
        const short* cb = colf + cur * 4096;
#pragma unroll
        for (int ksi = 0; ksi < 2; ++ksi) {
            bf8 a[4];
#pragma unroll
            for (int m = 0; m < 4; ++m)
                a[m] = *(const bf8*)(cb + ((m * 2 + ksi) * 64 + lane) * 8);
#pragma unroll
            for (int m = 0; m < 4; ++m) {
                acc[m][0] = __builtin_amdgcn_mfma_f32_16x16x32_bf16(a[m], bfr0[ksi], acc[m][0], 0, 0, 0);
                acc[m][1] = __builtin_amdgcn_mfma_f32_16x16x32_bf16(a[m], bfr1[ksi], acc[m][1], 0, 0, 0);
            }
        }

        // convert + write next tile to the other buffer (vmcnt wait lands here)
        if (kk < 8) INTERP_WRITE(nxt);
        __syncthreads();
    }
#undef GATHER_ISSUE
#undef INTERP_WRITE

    // ---- epilogue: C/D layout col=lane&15 (oc), row=(lane>>4)*4+r (px).
    //      LDS transpose per octile -> coalesced stores. ----
    float* ep = (float*)(smem + wave * 4352);    // f32[16][68]
    float* outb = out + (size_t)b * 128 * 4096 + ho * 64;
    const int ocl = lane & 15, hi = lane >> 4;
    const int ocr = lane >> 2, px0 = (lane & 3) * 16;
#pragma unroll
    for (int j = 0; j < 2; ++j) {
#pragma unroll
        for (int m = 0; m < 4; ++m)
            *(f32x4*)(ep + ocl * 68 + m * 16 + hi * 4) = acc[m][j];
        int ocg = (2 * wave + j) * 16 + ocr;
#pragma unroll
        for (int q = 0; q < 4; ++q) {
            f32x4 v = *(const f32x4*)(ep + ocr * 68 + px0 + q * 4);
            *(f32x4*)(outb + (size_t)ocg * 4096 + px0 + q * 4) = v;
        }
    }
}

extern "C" void kernel_launch(void* const* d_in, const int* in_sizes, int n_in,
                              void* d_out, int out_size, void* d_ws, size_t ws_size,
                              hipStream_t stream) {
    const float* x = (const float*)d_in[0];
    const float* offset = (const float*)d_in[1];
    const float* wgt = (const float*)d_in[2];
    float* out = (float*)d_out;
    u16* xtb = (u16*)d_ws;                              // 8.39 MB bf16 NHWC
    short* wfrag = (short*)(xtb + (size_t)16 * 64 * 64 * 64);  // 73728 bf16

    hipLaunchKernelGGL(transpose_x_kernel, dim3(1024), dim3(256), 0, stream, x, xtb);
    hipLaunchKernelGGL(build_wfrag, dim3(288), dim3(256), 0, stream, wgt, wfrag);
    hipLaunchKernelGGL(deform_main, dim3(1024), dim3(256), 0, stream, xtb, offset, wfrag, out);
}